// Round 6
// baseline (290.355 us; speedup 1.0000x reference)
//
#include <hip/hip_runtime.h>

#define B_   8
#define S_   4096
#define D_   1024
#define M_   (B_ * S_)   // 32768 rows
#define N_   (2 * D_)    // 2048 cols (hidden | gate)
#define K_   D_          // 1024
#define CCH  128         // scan chunks
#define LCH  32          // chunk length (CCH*LCH == S_)

#define BK   32
#define NT   (K_ / BK)   // 32 k-tiles

typedef __attribute__((ext_vector_type(8))) short bf16x8;
typedef __attribute__((ext_vector_type(4))) float f32x4;

__device__ __forceinline__ unsigned short f2bf(float f) {
  union { float f; unsigned u; } v; v.f = f;
  unsigned u = v.u;
  u = u + 0x7fffu + ((u >> 16) & 1u);   // RNE
  return (unsigned short)(u >> 16);
}
__device__ __forceinline__ float bf2f(unsigned short h) {
  union { unsigned u; float f; } v; v.u = ((unsigned)h) << 16;
  return v.f;
}
__device__ __forceinline__ float sigmoidf_(float x) {
  return 1.0f / (1.0f + __expf(-x));
}

#define GLL(src, dst) __builtin_amdgcn_global_load_lds(                     \
      (const __attribute__((address_space(1))) void*)(src),                 \
      (__attribute__((address_space(3))) void*)(dst), 16, 0, 0)

// ---------- fp32 -> bf16 convert (x4 vectorized, grid-stride) ----------
__global__ __launch_bounds__(256) void k_cvt(const float* __restrict__ in,
                                             unsigned short* __restrict__ out,
                                             int n4) {
  int i = blockIdx.x * 256 + threadIdx.x;
  const int stride = gridDim.x * 256;
  for (; i < n4; i += stride) {
    float4 v = reinterpret_cast<const float4*>(in)[i];
    ushort4 o;
    o.x = f2bf(v.x); o.y = f2bf(v.y); o.z = f2bf(v.z); o.w = f2bf(v.w);
    reinterpret_cast<ushort4*>(out)[i] = o;
  }
}

// ---------- bf16 GEMM: 128x128 tile, BK=32, 4 waves, 3-WG/CU occupancy ------
// Occupancy is the lever this round: 48KB LDS ring + <=170 unified regs
// (__launch_bounds__(256,3)) -> 3 WGs/CU = 3 waves/SIMD; cross-WG overlap
// fills the barrier/vmcnt shadows that capped 2-wave/SIMD configs at ~27%.
// 3-slot LDS ring, 2-tiles-ahead prefetch, counted vmcnt(4) (never 0 in
// steady state). XOR swizzle blk^=row&3 (64B rows), linear GLL dest +
// pre-swizzled global source (involution verified R3-R5).
__global__ __launch_bounds__(256, 3) void k_gemm(const unsigned short* __restrict__ xb,
                                                 const unsigned short* __restrict__ wb,
                                                 unsigned short* __restrict__ Gp,
                                                 unsigned short* __restrict__ Zp) {
  // 3 slots x (A 128x32 8KB | B 128x32 8KB) = 48 KiB
  __shared__ unsigned short lds[24576];
  const int tid = threadIdx.x;
  int wg = blockIdx.x;
  wg = (wg & 7) * 512 + (wg >> 3);     // XCD swizzle; 4096 % 8 == 0 -> bijective
  const int bm = wg >> 4;              // 0..255
  const int bn = wg & 15;              // 0..15
  const int lane = tid & 63;
  const int wid = tid >> 6;
  const int wr = wid >> 1;             // 0..1 (64-row band)
  const int wc = wid & 1;              // 0..1 (64-col band)
  const int fr = lane & 15;
  const int hi = lane >> 4;            // 0..3

  // staging: srow = tid>>2 (0..63), sblk = tid&3; LDS dest linear tid*16;
  // source block pre-swizzled so LDS[row][blk] holds global block blk^(row&3)
  const int srow = tid >> 2;
  const int scol = ((tid & 3) ^ (srow & 3)) * 16;
  const char* aS = (const char*)xb + (size_t)(bm * 128 + srow) * 2048 + scol;
  const char* bS = (const char*)wb + (size_t)(bn * 128 + srow) * 2048 + scol;
  char* const ldsc = (char*)lds + (size_t)tid * 16;   // per-thread stage dest
  const char* const ldsr = (const char*)lds;          // read base

  // frag read: row = band + m*16 + fr (row&3 == fr&3); byte col swizzled
  const int sA = ((hi ^ (fr & 3)) * 16);
  const int arow = (wr * 64 + fr) * 64;   // byte offset of av row base (m=0)
  const int brow = (wc * 64 + fr) * 64;

  f32x4 acc[4][4] = {};
  bf16x8 av[4], bv[4];

  // prologue: tile0 -> slot0, tile1 -> slot1 (8 GLL in flight), wait oldest 4
  GLL(aS,          ldsc);          GLL(aS + 131072,      ldsc + 4096);
  GLL(bS,          ldsc + 8192);   GLL(bS + 131072,      ldsc + 12288);
  GLL(aS + 64,     ldsc + 16384);  GLL(aS + 131072 + 64, ldsc + 20480);
  GLL(bS + 64,     ldsc + 24576);  GLL(bS + 131072 + 64, ldsc + 28672);
  asm volatile("s_waitcnt vmcnt(4)\n\ts_barrier" ::: "memory");

  int sl = 0;       // read slot byte base
  int sn = 32768;   // stage slot byte base (slot 2)

  for (int t = 0; t < NT; ++t) {
    const bool st2 = (t < NT - 2);
    if (st2) {      // stage tile t+2 into freed slot
      const size_t kb = (size_t)(t + 2) * 64;
      char* dq = ldsc + sn;
      GLL(aS + kb,          dq);          GLL(aS + 131072 + kb, dq + 4096);
      GLL(bS + kb,          dq + 8192);   GLL(bS + 131072 + kb, dq + 12288);
    }
    const char* Ab = ldsr + sl;
    const char* Bb = Ab + 8192;
#pragma unroll
    for (int m = 0; m < 4; ++m)
      av[m] = *(const bf16x8*)(Ab + arow + m * 1024 + sA);
#pragma unroll
    for (int n = 0; n < 4; ++n)
      bv[n] = *(const bf16x8*)(Bb + brow + n * 1024 + sA);
    __builtin_amdgcn_s_setprio(1);
#pragma unroll
    for (int m = 0; m < 4; ++m)
#pragma unroll
      for (int n = 0; n < 4; ++n)
        acc[m][n] = __builtin_amdgcn_mfma_f32_16x16x32_bf16(av[m], bv[n], acc[m][n], 0, 0, 0);
    __builtin_amdgcn_s_setprio(0);
    // end of tile t: ensure loads(t+1) landed; loads(t+2) may stay in flight
    if (st2) asm volatile("s_waitcnt vmcnt(4)\n\ts_barrier" ::: "memory");
    else     asm volatile("s_waitcnt vmcnt(0)\n\ts_barrier" ::: "memory");
    sl += 16384; if (sl == 49152) sl = 0;
    sn += 16384; if (sn == 49152) sn = 0;
  }

  // epilogue: C/D layout col = lane&15, row = (lane>>4)*4 + reg  [m89-verified]
  const int row0 = bm * 128 + wr * 64 + (hi << 2);
  const int col0 = bn * 128 + wc * 64 + fr;
  if (bn < 8) {  // hidden half -> g(hidden)
#pragma unroll
    for (int m = 0; m < 4; ++m)
#pragma unroll
      for (int n = 0; n < 4; ++n)
#pragma unroll
        for (int i = 0; i < 4; ++i) {
          float v = acc[m][n][i];
          float g = (v >= 0.0f) ? (v + 0.5f) : sigmoidf_(v);
          Gp[(size_t)(row0 + m * 16 + i) * 1024 + (col0 + n * 16)] = f2bf(g);
        }
  } else {       // gate half -> z = sigmoid(gate)
#pragma unroll
    for (int m = 0; m < 4; ++m)
#pragma unroll
      for (int n = 0; n < 4; ++n)
#pragma unroll
        for (int i = 0; i < 4; ++i) {
          float v = acc[m][n][i];
          Zp[(size_t)(row0 + m * 16 + i) * 1024 + (col0 + n * 16 - 1024)] = f2bf(sigmoidf_(v));
        }
  }
}

// ---------- scan phase 1: per-chunk local scan (h from 0) + a-product ----------
__global__ __launch_bounds__(256) void k_scan1(const unsigned short* __restrict__ Gp,
                                               const unsigned short* __restrict__ Zp,
                                               float* __restrict__ Ap,
                                               float* __restrict__ Hp) {
  const int gid = blockIdx.x * 256 + threadIdx.x;   // 0..2047
  const int c = blockIdx.y;
  const int b = gid >> 8;
  const int d0 = (gid & 255) << 2;
  size_t base = ((size_t)b * S_ + (size_t)c * LCH) * 1024 + d0;
  float4 aP = {1.f, 1.f, 1.f, 1.f};
  float4 h  = {0.f, 0.f, 0.f, 0.f};
#pragma unroll 8
  for (int s = 0; s < LCH; ++s) {
    ushort4 zu = *reinterpret_cast<const ushort4*>(Zp + base);
    ushort4 gu = *reinterpret_cast<const ushort4*>(Gp + base);
    float z0 = bf2f(zu.x), z1 = bf2f(zu.y), z2 = bf2f(zu.z), z3 = bf2f(zu.w);
    float a0 = 1.f - z0,   a1 = 1.f - z1,   a2 = 1.f - z2,   a3 = 1.f - z3;
    h.x = fmaf(a0, h.x, z0 * bf2f(gu.x));
    h.y = fmaf(a1, h.y, z1 * bf2f(gu.y));
    h.z = fmaf(a2, h.z, z2 * bf2f(gu.z));
    h.w = fmaf(a3, h.w, z3 * bf2f(gu.w));
    aP.x *= a0; aP.y *= a1; aP.z *= a2; aP.w *= a3;
    base += 1024;
  }
  reinterpret_cast<float4*>(Ap)[(size_t)c * 2048 + gid] = aP;
  reinterpret_cast<float4*>(Hp)[(size_t)c * 2048 + gid] = h;
}

// ---------- scan phase 2: sequential carry over chunks ----------
__global__ __launch_bounds__(256) void k_scan2(const float* __restrict__ Ap,
                                               const float* __restrict__ Hp,
                                               float* __restrict__ Cin) {
  const int gid = blockIdx.x * 256 + threadIdx.x;   // 0..2047
  float4 carry = {0.f, 0.f, 0.f, 0.f};
  for (int c = 0; c < CCH; ++c) {
    reinterpret_cast<float4*>(Cin)[(size_t)c * 2048 + gid] = carry;
    float4 a = reinterpret_cast<const float4*>(Ap)[(size_t)c * 2048 + gid];
    float4 hh = reinterpret_cast<const float4*>(Hp)[(size_t)c * 2048 + gid];
    carry.x = fmaf(a.x, carry.x, hh.x);
    carry.y = fmaf(a.y, carry.y, hh.y);
    carry.z = fmaf(a.z, carry.z, hh.z);
    carry.w = fmaf(a.w, carry.w, hh.w);
  }
}

// ---------- scan phase 3: replay with carry, write fp32 out ----------
__global__ __launch_bounds__(256) void k_scan3(const unsigned short* __restrict__ Gp,
                                               const unsigned short* __restrict__ Zp,
                                               const float* __restrict__ Cin,
                                               float* __restrict__ out) {
  const int gid = blockIdx.x * 256 + threadIdx.x;
  const int c = blockIdx.y;
  const int b = gid >> 8;
  const int d0 = (gid & 255) << 2;
  size_t base = ((size_t)b * S_ + (size_t)c * LCH) * 1024 + d0;
  float4 h = reinterpret_cast<const float4*>(Cin)[(size_t)c * 2048 + gid];
#pragma unroll 8
  for (int s = 0; s < LCH; ++s) {
    ushort4 zu = *reinterpret_cast<const ushort4*>(Zp + base);
    ushort4 gu = *reinterpret_cast<const ushort4*>(Gp + base);
    float z0 = bf2f(zu.x), z1 = bf2f(zu.y), z2 = bf2f(zu.z), z3 = bf2f(zu.w);
    h.x = fmaf(1.f - z0, h.x, z0 * bf2f(gu.x));
    h.y = fmaf(1.f - z1, h.y, z1 * bf2f(gu.y));
    h.z = fmaf(1.f - z2, h.z, z2 * bf2f(gu.z));
    h.w = fmaf(1.f - z3, h.w, z3 * bf2f(gu.w));
    *reinterpret_cast<float4*>(out + base) = h;
    base += 1024;
  }
}

extern "C" void kernel_launch(void* const* d_in, const int* in_sizes, int n_in,
                              void* d_out, int out_size, void* d_ws, size_t ws_size,
                              hipStream_t stream) {
  const float* x = (const float*)d_in[0];   // [8,4096,1024] f32
  const float* W = (const float*)d_in[1];   // [2048,1024]  f32
  float* out = (float*)d_out;               // [8,4096,1024] f32

  unsigned char* w = (unsigned char*)d_ws;
  // layout: xb(64MB) | wb(4MB) | Gp(64MB) | Zp(64MB). Ap/Hp/Cin alias xb
  // (xb is dead after k_gemm; 3 x 4MB << 64MB).
  unsigned short* xb = (unsigned short*)(w);
  unsigned short* wb = (unsigned short*)(w + 67108864);
  unsigned short* Gp = (unsigned short*)(w + 67108864 + 4194304);
  unsigned short* Zp = (unsigned short*)(w + 67108864 + 4194304 + 67108864);
  float* Ap  = (float*)(w);
  float* Hp  = (float*)(w + 4194304);
  float* Cin = (float*)(w + 8388608);

  k_cvt<<<4096, 256, 0, stream>>>(x, xb, (M_ * K_) / 4);
  k_cvt<<<2048, 256, 0, stream>>>(W, wb, (N_ * K_) / 4);
  k_gemm<<<(M_ / 128) * (N_ / 128), 256, 0, stream>>>(xb, wb, Gp, Zp);
  k_scan1<<<dim3(8, CCH), 256, 0, stream>>>(Gp, Zp, Ap, Hp);
  k_scan2<<<8, 256, 0, stream>>>(Ap, Hp, Cin);
  k_scan3<<<dim3(8, CCH), 256, 0, stream>>>(Gp, Zp, Cin, out);
}

// Round 7
// 287.561 us; speedup vs baseline: 1.0097x; 1.0097x over previous
//
#include <hip/hip_runtime.h>

#define B_   8
#define S_   4096
#define D_   1024
#define M_   (B_ * S_)   // 32768 rows
#define N_   (2 * D_)    // 2048 cols (hidden | gate)
#define K_   D_          // 1024
#define CCH  128         // scan chunks
#define LCH  32          // chunk length (CCH*LCH == S_)

#define BK   32
#define NT   (K_ / BK)   // 32 k-tiles

typedef __attribute__((ext_vector_type(8))) short bf16x8;
typedef __attribute__((ext_vector_type(4))) float f32x4;

__device__ __forceinline__ unsigned short f2bf(float f) {
  union { float f; unsigned u; } v; v.f = f;
  unsigned u = v.u;
  u = u + 0x7fffu + ((u >> 16) & 1u);   // RNE
  return (unsigned short)(u >> 16);
}
__device__ __forceinline__ float bf2f(unsigned short h) {
  union { unsigned u; float f; } v; v.u = ((unsigned)h) << 16;
  return v.f;
}
__device__ __forceinline__ float sigmoidf_(float x) {
  return 1.0f / (1.0f + __expf(-x));
}

#define GLL(src, dst) __builtin_amdgcn_global_load_lds(                     \
      (const __attribute__((address_space(1))) void*)(src),                 \
      (__attribute__((address_space(3))) void*)(dst), 16, 0, 0)

// ---------- fp32 -> bf16 convert, x and W in one launch ----------
__global__ __launch_bounds__(256) void k_cvt2(const float* __restrict__ x,
                                              const float* __restrict__ W,
                                              unsigned short* __restrict__ xb,
                                              unsigned short* __restrict__ wb) {
  const int n4x = (M_ * K_) / 4;             // 8388608
  const int n4t = n4x + (N_ * K_) / 4;       // + 524288
  int i = blockIdx.x * 256 + threadIdx.x;
  const int stride = gridDim.x * 256;
  for (; i < n4t; i += stride) {
    const float4* src = (i < n4x) ? &reinterpret_cast<const float4*>(x)[i]
                                  : &reinterpret_cast<const float4*>(W)[i - n4x];
    float4 v = *src;
    ushort4 o;
    o.x = f2bf(v.x); o.y = f2bf(v.y); o.z = f2bf(v.z); o.w = f2bf(v.w);
    if (i < n4x) reinterpret_cast<ushort4*>(xb)[i] = o;
    else         reinterpret_cast<ushort4*>(wb)[i - n4x] = o;
  }
}

// ---------- bf16 GEMM: 128x128 tile, BK=32, 4 waves, 3-WG/CU occupancy ------
// R7 change: PAIR-ROW swizzle. 64B rows only span 4 of 8 16B-slots, so the
// bijection must mix across row pairs: logical blk j of row r lives at
// physical slot j ^ ((r>>1)&3). Every read-octet then covers all 8 slots
// (enumerated), GLL writes stay linear/conflict-free. Staging source col and
// read col both updated (both-sides involution, rule #21).
__global__ __launch_bounds__(256, 3) void k_gemm(const unsigned short* __restrict__ xb,
                                                 const unsigned short* __restrict__ wb,
                                                 unsigned short* __restrict__ Gp,
                                                 unsigned short* __restrict__ Zp) {
  // 3 slots x (A 128x32 8KB | B 128x32 8KB) = 48 KiB
  __shared__ unsigned short lds[24576];
  const int tid = threadIdx.x;
  int wg = blockIdx.x;
  wg = (wg & 7) * 512 + (wg >> 3);     // XCD swizzle; 4096 % 8 == 0 -> bijective
  const int bm = wg >> 4;              // 0..255
  const int bn = wg & 15;              // 0..15
  const int lane = tid & 63;
  const int wid = tid >> 6;
  const int wr = wid >> 1;             // 0..1 (64-row band)
  const int wc = wid & 1;              // 0..1 (64-col band)
  const int fr = lane & 15;
  const int hi = lane >> 4;            // 0..3

  // staging: srow = tid>>2 (0..63), slot i = tid&3; LDS dest linear tid*16;
  // fetch logical blk j = i ^ ((srow>>1)&3) so phys slot i holds j.
  const int srow = tid >> 2;
  const int scol = ((tid & 3) ^ ((srow >> 1) & 3)) * 16;
  const char* aS = (const char*)xb + (size_t)(bm * 128 + srow) * 2048 + scol;
  const char* bS = (const char*)wb + (size_t)(bn * 128 + srow) * 2048 + scol;
  char* const ldsc = (char*)lds + (size_t)tid * 16;   // per-thread stage dest
  const char* const ldsr = (const char*)lds;          // read base

  // frag read: row = band + m*16 + fr; (row>>1)&3 == (fr>>1)&3 (band,m*16 are
  // multiples of 16). logical blk = hi -> phys slot hi ^ ((fr>>1)&3).
  const int sA = ((hi ^ ((fr >> 1) & 3)) * 16);
  const int arow = (wr * 64 + fr) * 64;   // byte offset of av row base (m=0)
  const int brow = (wc * 64 + fr) * 64;

  f32x4 acc[4][4] = {};
  bf16x8 av[4], bv[4];

  // prologue: tile0 -> slot0, tile1 -> slot1 (8 GLL in flight), wait oldest 4
  GLL(aS,          ldsc);          GLL(aS + 131072,      ldsc + 4096);
  GLL(bS,          ldsc + 8192);   GLL(bS + 131072,      ldsc + 12288);
  GLL(aS + 64,     ldsc + 16384);  GLL(aS + 131072 + 64, ldsc + 20480);
  GLL(bS + 64,     ldsc + 24576);  GLL(bS + 131072 + 64, ldsc + 28672);
  asm volatile("s_waitcnt vmcnt(4)\n\ts_barrier" ::: "memory");

  int sl = 0;       // read slot byte base
  int sn = 32768;   // stage slot byte base (slot 2)

  for (int t = 0; t < NT; ++t) {
    const bool st2 = (t < NT - 2);
    if (st2) {      // stage tile t+2 into freed slot
      const size_t kb = (size_t)(t + 2) * 64;
      char* dq = ldsc + sn;
      GLL(aS + kb,          dq);          GLL(aS + 131072 + kb, dq + 4096);
      GLL(bS + kb,          dq + 8192);   GLL(bS + 131072 + kb, dq + 12288);
    }
    const char* Ab = ldsr + sl;
    const char* Bb = Ab + 8192;
#pragma unroll
    for (int m = 0; m < 4; ++m)
      av[m] = *(const bf16x8*)(Ab + arow + m * 1024 + sA);
#pragma unroll
    for (int n = 0; n < 4; ++n)
      bv[n] = *(const bf16x8*)(Bb + brow + n * 1024 + sA);
    __builtin_amdgcn_s_setprio(1);
#pragma unroll
    for (int m = 0; m < 4; ++m)
#pragma unroll
      for (int n = 0; n < 4; ++n)
        acc[m][n] = __builtin_amdgcn_mfma_f32_16x16x32_bf16(av[m], bv[n], acc[m][n], 0, 0, 0);
    __builtin_amdgcn_s_setprio(0);
    // end of tile t: ensure loads(t+1) landed; loads(t+2) may stay in flight
    if (st2) asm volatile("s_waitcnt vmcnt(4)\n\ts_barrier" ::: "memory");
    else     asm volatile("s_waitcnt vmcnt(0)\n\ts_barrier" ::: "memory");
    sl += 16384; if (sl == 49152) sl = 0;
    sn += 16384; if (sn == 49152) sn = 0;
  }

  // epilogue: C/D layout col = lane&15, row = (lane>>4)*4 + reg  [m89-verified]
  const int row0 = bm * 128 + wr * 64 + (hi << 2);
  const int col0 = bn * 128 + wc * 64 + fr;
  if (bn < 8) {  // hidden half -> g(hidden)
#pragma unroll
    for (int m = 0; m < 4; ++m)
#pragma unroll
      for (int n = 0; n < 4; ++n)
#pragma unroll
        for (int i = 0; i < 4; ++i) {
          float v = acc[m][n][i];
          float g = (v >= 0.0f) ? (v + 0.5f) : sigmoidf_(v);
          Gp[(size_t)(row0 + m * 16 + i) * 1024 + (col0 + n * 16)] = f2bf(g);
        }
  } else {       // gate half -> z = sigmoid(gate)
#pragma unroll
    for (int m = 0; m < 4; ++m)
#pragma unroll
      for (int n = 0; n < 4; ++n)
#pragma unroll
        for (int i = 0; i < 4; ++i) {
          float v = acc[m][n][i];
          Zp[(size_t)(row0 + m * 16 + i) * 1024 + (col0 + n * 16 - 1024)] = f2bf(sigmoidf_(v));
        }
  }
}

// ---------- scan phase 1: per-chunk local scan (h from 0) + a-product ----------
__global__ __launch_bounds__(256) void k_scan1(const unsigned short* __restrict__ Gp,
                                               const unsigned short* __restrict__ Zp,
                                               float* __restrict__ Ap,
                                               float* __restrict__ Hp) {
  const int gid = blockIdx.x * 256 + threadIdx.x;   // 0..2047
  const int c = blockIdx.y;
  const int b = gid >> 8;
  const int d0 = (gid & 255) << 2;
  size_t base = ((size_t)b * S_ + (size_t)c * LCH) * 1024 + d0;
  float4 aP = {1.f, 1.f, 1.f, 1.f};
  float4 h  = {0.f, 0.f, 0.f, 0.f};
#pragma unroll 8
  for (int s = 0; s < LCH; ++s) {
    ushort4 zu = *reinterpret_cast<const ushort4*>(Zp + base);
    ushort4 gu = *reinterpret_cast<const ushort4*>(Gp + base);
    float z0 = bf2f(zu.x), z1 = bf2f(zu.y), z2 = bf2f(zu.z), z3 = bf2f(zu.w);
    float a0 = 1.f - z0,   a1 = 1.f - z1,   a2 = 1.f - z2,   a3 = 1.f - z3;
    h.x = fmaf(a0, h.x, z0 * bf2f(gu.x));
    h.y = fmaf(a1, h.y, z1 * bf2f(gu.y));
    h.z = fmaf(a2, h.z, z2 * bf2f(gu.z));
    h.w = fmaf(a3, h.w, z3 * bf2f(gu.w));
    aP.x *= a0; aP.y *= a1; aP.z *= a2; aP.w *= a3;
    base += 1024;
  }
  reinterpret_cast<float4*>(Ap)[(size_t)c * 2048 + gid] = aP;
  reinterpret_cast<float4*>(Hp)[(size_t)c * 2048 + gid] = h;
}

// ---------- scan phase 2: sequential carry over chunks ----------
__global__ __launch_bounds__(256) void k_scan2(const float* __restrict__ Ap,
                                               const float* __restrict__ Hp,
                                               float* __restrict__ Cin) {
  const int gid = blockIdx.x * 256 + threadIdx.x;   // 0..2047
  float4 carry = {0.f, 0.f, 0.f, 0.f};
  for (int c = 0; c < CCH; ++c) {
    reinterpret_cast<float4*>(Cin)[(size_t)c * 2048 + gid] = carry;
    float4 a = reinterpret_cast<const float4*>(Ap)[(size_t)c * 2048 + gid];
    float4 hh = reinterpret_cast<const float4*>(Hp)[(size_t)c * 2048 + gid];
    carry.x = fmaf(a.x, carry.x, hh.x);
    carry.y = fmaf(a.y, carry.y, hh.y);
    carry.z = fmaf(a.z, carry.z, hh.z);
    carry.w = fmaf(a.w, carry.w, hh.w);
  }
}

// ---------- scan phase 3: replay with carry, write fp32 out ----------
__global__ __launch_bounds__(256) void k_scan3(const unsigned short* __restrict__ Gp,
                                               const unsigned short* __restrict__ Zp,
                                               const float* __restrict__ Cin,
                                               float* __restrict__ out) {
  const int gid = blockIdx.x * 256 + threadIdx.x;
  const int c = blockIdx.y;
  const int b = gid >> 8;
  const int d0 = (gid & 255) << 2;
  size_t base = ((size_t)b * S_ + (size_t)c * LCH) * 1024 + d0;
  float4 h = reinterpret_cast<const float4*>(Cin)[(size_t)c * 2048 + gid];
#pragma unroll 8
  for (int s = 0; s < LCH; ++s) {
    ushort4 zu = *reinterpret_cast<const ushort4*>(Zp + base);
    ushort4 gu = *reinterpret_cast<const ushort4*>(Gp + base);
    float z0 = bf2f(zu.x), z1 = bf2f(zu.y), z2 = bf2f(zu.z), z3 = bf2f(zu.w);
    h.x = fmaf(1.f - z0, h.x, z0 * bf2f(gu.x));
    h.y = fmaf(1.f - z1, h.y, z1 * bf2f(gu.y));
    h.z = fmaf(1.f - z2, h.z, z2 * bf2f(gu.z));
    h.w = fmaf(1.f - z3, h.w, z3 * bf2f(gu.w));
    *reinterpret_cast<float4*>(out + base) = h;
    base += 1024;
  }
}

extern "C" void kernel_launch(void* const* d_in, const int* in_sizes, int n_in,
                              void* d_out, int out_size, void* d_ws, size_t ws_size,
                              hipStream_t stream) {
  const float* x = (const float*)d_in[0];   // [8,4096,1024] f32
  const float* W = (const float*)d_in[1];   // [2048,1024]  f32
  float* out = (float*)d_out;               // [8,4096,1024] f32

  unsigned char* w = (unsigned char*)d_ws;
  // layout: xb(64MB) | wb(4MB) | Gp(64MB) | Zp(64MB). Ap/Hp/Cin alias xb
  // (xb is dead after k_gemm; 3 x 4MB << 64MB).
  unsigned short* xb = (unsigned short*)(w);
  unsigned short* wb = (unsigned short*)(w + 67108864);
  unsigned short* Gp = (unsigned short*)(w + 67108864 + 4194304);
  unsigned short* Zp = (unsigned short*)(w + 67108864 + 4194304 + 67108864);
  float* Ap  = (float*)(w);
  float* Hp  = (float*)(w + 4194304);
  float* Cin = (float*)(w + 8388608);

  k_cvt2<<<4096, 256, 0, stream>>>(x, W, xb, wb);
  k_gemm<<<(M_ / 128) * (N_ / 128), 256, 0, stream>>>(xb, wb, Gp, Zp);
  k_scan1<<<dim3(8, CCH), 256, 0, stream>>>(Gp, Zp, Ap, Hp);
  k_scan2<<<8, 256, 0, stream>>>(Ap, Hp, Cin);
  k_scan3<<<dim3(8, CCH), 256, 0, stream>>>(Gp, Zp, Cin, out);
}

// Round 8
// 273.579 us; speedup vs baseline: 1.0613x; 1.0511x over previous
//
#include <hip/hip_runtime.h>

#define B_   8
#define S_   4096
#define D_   1024
#define M_   (B_ * S_)   // 32768 rows
#define N_   (2 * D_)    // 2048 cols (hidden | gate)
#define K_   D_          // 1024
#define CCH  128         // scan chunks
#define LCH  32          // chunk length (CCH*LCH == S_)

#define BK   32
#define NT   (K_ / BK)   // 32 k-tiles

typedef __attribute__((ext_vector_type(8))) short bf16x8;
typedef __attribute__((ext_vector_type(4))) float f32x4;

__device__ __forceinline__ unsigned short f2bf(float f) {
  union { float f; unsigned u; } v; v.f = f;
  unsigned u = v.u;
  u = u + 0x7fffu + ((u >> 16) & 1u);   // RNE
  return (unsigned short)(u >> 16);
}
__device__ __forceinline__ float bf2f(unsigned short h) {
  union { unsigned u; float f; } v; v.u = ((unsigned)h) << 16;
  return v.f;
}
__device__ __forceinline__ float sigmoidf_(float x) {
  return 1.0f / (1.0f + __expf(-x));
}

#define GLL(src, dst) __builtin_amdgcn_global_load_lds(                     \
      (const __attribute__((address_space(1))) void*)(src),                 \
      (__attribute__((address_space(3))) void*)(dst), 16, 0, 0)

// ---------- fp32 -> bf16 convert, x and W in one launch ----------
__global__ __launch_bounds__(256) void k_cvt2(const float* __restrict__ x,
                                              const float* __restrict__ W,
                                              unsigned short* __restrict__ xb,
                                              unsigned short* __restrict__ wb) {
  const int n4x = (M_ * K_) / 4;             // 8388608
  const int n4t = n4x + (N_ * K_) / 4;       // + 524288
  int i = blockIdx.x * 256 + threadIdx.x;
  const int stride = gridDim.x * 256;
  for (; i < n4t; i += stride) {
    const float4* src = (i < n4x) ? &reinterpret_cast<const float4*>(x)[i]
                                  : &reinterpret_cast<const float4*>(W)[i - n4x];
    float4 v = *src;
    ushort4 o;
    o.x = f2bf(v.x); o.y = f2bf(v.y); o.z = f2bf(v.z); o.w = f2bf(v.w);
    if (i < n4x) reinterpret_cast<ushort4*>(xb)[i] = o;
    else         reinterpret_cast<ushort4*>(wb)[i - n4x] = o;
  }
}

// ---------- bf16 GEMM: 256x128 tile, BK=32, 8 waves, 2 WG/CU = 4 waves/SIMD --
// R8 change: fatter tile in the M direction at constant per-wave shape.
// 8 waves (4M x 2N), per-wave 64x64 / acc4x4 (VGPR ~<=100). LDS slot =
// A 16KB + B 8KB = 24KB; 3-slot ring = 72KB -> 2 WGs/CU = 16 waves/CU
// (4 waves/SIMD vs R7's 3). Halves per-output B staging traffic; halves
// block count. Keeps: counted vmcnt(3) 2-ahead ring (T4), pair-row swizzle
// (0 conflicts, R7-verified), XCD swizzle, setprio.
__global__ __launch_bounds__(512, 4) void k_gemm(const unsigned short* __restrict__ xb,
                                                 const unsigned short* __restrict__ wb,
                                                 unsigned short* __restrict__ Gp,
                                                 unsigned short* __restrict__ Zp) {
  // 3 slots x (A 256x32 16KB | B 128x32 8KB) = 72 KiB
  __shared__ unsigned short lds[36864];
  const int tid = threadIdx.x;
  int wg = blockIdx.x;
  wg = (wg & 7) * 256 + (wg >> 3);     // XCD swizzle; 2048 % 8 == 0 -> bijective
  const int bm = wg >> 4;              // 0..127  (256-row panels)
  const int bn = wg & 15;              // 0..15   (128-col panels)
  const int lane = tid & 63;
  const int wid = tid >> 6;            // 0..7
  const int wrr = wid >> 1;            // 0..3 (64-row band)
  const int wcc = wid & 1;             // 0..1 (64-col band)
  const int fr = lane & 15;
  const int hi = lane >> 4;            // 0..3

  // staging: srow = tid>>2 (0..127), slot i = tid&3; LDS dest linear tid*16;
  // fetch logical blk j = i ^ ((srow>>1)&3) so phys slot i holds j (pair-row
  // swizzle: 64B rows span 4 slots; mixing across row pairs covers all 8).
  const int srow = tid >> 2;
  const int scol = ((tid & 3) ^ ((srow >> 1) & 3)) * 16;
  const char* aS = (const char*)xb + (size_t)(bm * 256 + srow) * 2048 + scol;
  const char* bS = (const char*)wb + (size_t)(bn * 128 + srow) * 2048 + scol;
  char* const ldsc = (char*)lds + (size_t)tid * 16;   // per-thread stage dest
  const char* const ldsr = (const char*)lds;          // read base

  // frag read: row = band + m*16 + fr; (row>>1)&3 == (fr>>1)&3. logical blk
  // hi -> phys slot hi ^ ((fr>>1)&3).
  const int sA = ((hi ^ ((fr >> 1) & 3)) * 16);
  const int arow = (wrr * 64 + fr) * 64;            // A: byte row base (m=0)
  const int brow = 16384 + (wcc * 64 + fr) * 64;    // B region at +16KB

  f32x4 acc[4][4] = {};
  bf16x8 av[4], bv[4];

  // prologue: tile0 -> slot0, tile1 -> slot1 (6 GLL in flight), wait oldest 3
  GLL(aS,               ldsc);           // t0 A rows 0-127
  GLL(aS + 262144,      ldsc + 8192);    // t0 A rows 128-255
  GLL(bS,               ldsc + 16384);   // t0 B
  GLL(aS + 64,          ldsc + 24576);
  GLL(aS + 262144 + 64, ldsc + 32768);
  GLL(bS + 64,          ldsc + 40960);
  asm volatile("s_waitcnt vmcnt(3)\n\ts_barrier" ::: "memory");

  int sl = 0;       // read slot byte base
  int sn = 49152;   // stage slot byte base (slot 2)

  for (int t = 0; t < NT; ++t) {
    const bool st2 = (t < NT - 2);
    if (st2) {      // stage tile t+2 into freed slot
      const size_t kb = (size_t)(t + 2) * 64;
      char* dq = ldsc + sn;
      GLL(aS + kb,               dq);
      GLL(aS + 262144 + kb,      dq + 8192);
      GLL(bS + kb,               dq + 16384);
    }
    const char* Ab = ldsr + sl;
#pragma unroll
    for (int m = 0; m < 4; ++m)
      av[m] = *(const bf16x8*)(Ab + arow + m * 1024 + sA);
#pragma unroll
    for (int n = 0; n < 4; ++n)
      bv[n] = *(const bf16x8*)(Ab + brow + n * 1024 + sA);
    __builtin_amdgcn_s_setprio(1);
#pragma unroll
    for (int m = 0; m < 4; ++m)
#pragma unroll
      for (int n = 0; n < 4; ++n)
        acc[m][n] = __builtin_amdgcn_mfma_f32_16x16x32_bf16(av[m], bv[n], acc[m][n], 0, 0, 0);
    __builtin_amdgcn_s_setprio(0);
    // end of tile t: ensure loads(t+1) landed; loads(t+2) may stay in flight
    if (st2) asm volatile("s_waitcnt vmcnt(3)\n\ts_barrier" ::: "memory");
    else     asm volatile("s_waitcnt vmcnt(0)\n\ts_barrier" ::: "memory");
    sl += 24576; if (sl == 73728) sl = 0;
    sn += 24576; if (sn == 73728) sn = 0;
  }

  // epilogue: C/D layout col = lane&15, row = (lane>>4)*4 + reg  [m89-verified]
  const int row0 = bm * 256 + wrr * 64 + (hi << 2);
  const int col0 = bn * 128 + wcc * 64 + fr;
  if (bn < 8) {  // hidden half -> g(hidden)
#pragma unroll
    for (int m = 0; m < 4; ++m)
#pragma unroll
      for (int n = 0; n < 4; ++n)
#pragma unroll
        for (int i = 0; i < 4; ++i) {
          float v = acc[m][n][i];
          float g = (v >= 0.0f) ? (v + 0.5f) : sigmoidf_(v);
          Gp[(size_t)(row0 + m * 16 + i) * 1024 + (col0 + n * 16)] = f2bf(g);
        }
  } else {       // gate half -> z = sigmoid(gate)
#pragma unroll
    for (int m = 0; m < 4; ++m)
#pragma unroll
      for (int n = 0; n < 4; ++n)
#pragma unroll
        for (int i = 0; i < 4; ++i) {
          float v = acc[m][n][i];
          Zp[(size_t)(row0 + m * 16 + i) * 1024 + (col0 + n * 16 - 1024)] = f2bf(sigmoidf_(v));
        }
  }
}

// ---------- scan phase 1: per-chunk local scan (h from 0) + a-product ----------
__global__ __launch_bounds__(256) void k_scan1(const unsigned short* __restrict__ Gp,
                                               const unsigned short* __restrict__ Zp,
                                               float* __restrict__ Ap,
                                               float* __restrict__ Hp) {
  const int gid = blockIdx.x * 256 + threadIdx.x;   // 0..2047
  const int c = blockIdx.y;
  const int b = gid >> 8;
  const int d0 = (gid & 255) << 2;
  size_t base = ((size_t)b * S_ + (size_t)c * LCH) * 1024 + d0;
  float4 aP = {1.f, 1.f, 1.f, 1.f};
  float4 h  = {0.f, 0.f, 0.f, 0.f};
#pragma unroll 8
  for (int s = 0; s < LCH; ++s) {
    ushort4 zu = *reinterpret_cast<const ushort4*>(Zp + base);
    ushort4 gu = *reinterpret_cast<const ushort4*>(Gp + base);
    float z0 = bf2f(zu.x), z1 = bf2f(zu.y), z2 = bf2f(zu.z), z3 = bf2f(zu.w);
    float a0 = 1.f - z0,   a1 = 1.f - z1,   a2 = 1.f - z2,   a3 = 1.f - z3;
    h.x = fmaf(a0, h.x, z0 * bf2f(gu.x));
    h.y = fmaf(a1, h.y, z1 * bf2f(gu.y));
    h.z = fmaf(a2, h.z, z2 * bf2f(gu.z));
    h.w = fmaf(a3, h.w, z3 * bf2f(gu.w));
    aP.x *= a0; aP.y *= a1; aP.z *= a2; aP.w *= a3;
    base += 1024;
  }
  reinterpret_cast<float4*>(Ap)[(size_t)c * 2048 + gid] = aP;
  reinterpret_cast<float4*>(Hp)[(size_t)c * 2048 + gid] = h;
}

// ---------- scan phase 2: sequential carry over chunks ----------
__global__ __launch_bounds__(256) void k_scan2(const float* __restrict__ Ap,
                                               const float* __restrict__ Hp,
                                               float* __restrict__ Cin) {
  const int gid = blockIdx.x * 256 + threadIdx.x;   // 0..2047
  float4 carry = {0.f, 0.f, 0.f, 0.f};
  for (int c = 0; c < CCH; ++c) {
    reinterpret_cast<float4*>(Cin)[(size_t)c * 2048 + gid] = carry;
    float4 a = reinterpret_cast<const float4*>(Ap)[(size_t)c * 2048 + gid];
    float4 hh = reinterpret_cast<const float4*>(Hp)[(size_t)c * 2048 + gid];
    carry.x = fmaf(a.x, carry.x, hh.x);
    carry.y = fmaf(a.y, carry.y, hh.y);
    carry.z = fmaf(a.z, carry.z, hh.z);
    carry.w = fmaf(a.w, carry.w, hh.w);
  }
}

// ---------- scan phase 3: replay with carry, write fp32 out ----------
__global__ __launch_bounds__(256) void k_scan3(const unsigned short* __restrict__ Gp,
                                               const unsigned short* __restrict__ Zp,
                                               const float* __restrict__ Cin,
                                               float* __restrict__ out) {
  const int gid = blockIdx.x * 256 + threadIdx.x;
  const int c = blockIdx.y;
  const int b = gid >> 8;
  const int d0 = (gid & 255) << 2;
  size_t base = ((size_t)b * S_ + (size_t)c * LCH) * 1024 + d0;
  float4 h = reinterpret_cast<const float4*>(Cin)[(size_t)c * 2048 + gid];
#pragma unroll 8
  for (int s = 0; s < LCH; ++s) {
    ushort4 zu = *reinterpret_cast<const ushort4*>(Zp + base);
    ushort4 gu = *reinterpret_cast<const ushort4*>(Gp + base);
    float z0 = bf2f(zu.x), z1 = bf2f(zu.y), z2 = bf2f(zu.z), z3 = bf2f(zu.w);
    h.x = fmaf(1.f - z0, h.x, z0 * bf2f(gu.x));
    h.y = fmaf(1.f - z1, h.y, z1 * bf2f(gu.y));
    h.z = fmaf(1.f - z2, h.z, z2 * bf2f(gu.z));
    h.w = fmaf(1.f - z3, h.w, z3 * bf2f(gu.w));
    *reinterpret_cast<float4*>(out + base) = h;
    base += 1024;
  }
}

extern "C" void kernel_launch(void* const* d_in, const int* in_sizes, int n_in,
                              void* d_out, int out_size, void* d_ws, size_t ws_size,
                              hipStream_t stream) {
  const float* x = (const float*)d_in[0];   // [8,4096,1024] f32
  const float* W = (const float*)d_in[1];   // [2048,1024]  f32
  float* out = (float*)d_out;               // [8,4096,1024] f32

  unsigned char* w = (unsigned char*)d_ws;
  // layout: xb(64MB) | wb(4MB) | Gp(64MB) | Zp(64MB). Ap/Hp/Cin alias xb
  // (xb is dead after k_gemm; 3 x 4MB << 64MB).
  unsigned short* xb = (unsigned short*)(w);
  unsigned short* wb = (unsigned short*)(w + 67108864);
  unsigned short* Gp = (unsigned short*)(w + 67108864 + 4194304);
  unsigned short* Zp = (unsigned short*)(w + 67108864 + 4194304 + 67108864);
  float* Ap  = (float*)(w);
  float* Hp  = (float*)(w + 4194304);
  float* Cin = (float*)(w + 8388608);

  k_cvt2<<<4096, 256, 0, stream>>>(x, W, xb, wb);
  k_gemm<<<(M_ / 256) * (N_ / 128), 512, 0, stream>>>(xb, wb, Gp, Zp);
  k_scan1<<<dim3(8, CCH), 256, 0, stream>>>(Gp, Zp, Ap, Hp);
  k_scan2<<<8, 256, 0, stream>>>(Ap, Hp, Cin);
  k_scan3<<<dim3(8, CCH), 256, 0, stream>>>(Gp, Zp, Cin, out);
}